// Round 1
// baseline (181.556 us; speedup 1.0000x reference)
//
#include <hip/hip_runtime.h>
#include <stdint.h>

// ---------------------------------------------------------------------------
// AudioVisualModel fused loss on MI355X.
// B=16, Na=128, T=10, Nv=196, D=256.
// Pipeline: prep (normalize->bf16, visual padded to 208/t + row-swizzled)
//           main (per-(x,y) block: fused MFMA GEMM + max/mean/nonneg reduce)
//           final (16x16 InfoNCE + reg terms)
// ---------------------------------------------------------------------------

typedef __bf16 bf16x8 __attribute__((ext_vector_type(8)));
typedef float  f32x4  __attribute__((ext_vector_type(4)));

// workspace layout (bytes)
#define WS_A_OFF    ((size_t)0)                         // a_n: 2048 x 256 bf16 = 1 MB
#define WS_V_OFF    ((size_t)(1u<<20))                  // v_swz: 16 x 2112 x 256 bf16 = 16.5 MB
#define WS_PART_OFF (WS_V_OFF + (size_t)16*2112*512)    // part: 256 pairs x 128 x 10 int
#define WS_CLIP_OFF (WS_PART_OFF + (size_t)256*1280*4)  // clip_raw: 256 f32
#define WS_NN_OFF   (WS_CLIP_OFF + (size_t)1024)        // nonneg partials: 256 f32

__device__ __forceinline__ unsigned short f2bf(float f) {
    unsigned b = __float_as_uint(f);
    return (unsigned short)((b + 0x7fffu + ((b >> 16) & 1u)) >> 16);   // RNE
}
// order-preserving float<->int for atomicMax
__device__ __forceinline__ int fenc(float f) {
    int i = __float_as_int(f);
    return i >= 0 ? i : (i ^ 0x7fffffff);
}
__device__ __forceinline__ float fdec(int i) {
    return __int_as_float(i >= 0 ? i : (i ^ 0x7fffffff));
}
__device__ __forceinline__ void gld_lds16(const char* g, char* l) {
    __builtin_amdgcn_global_load_lds(
        (const __attribute__((address_space(1))) void*)g,
        (__attribute__((address_space(3))) void*)l, 16, 0, 0);
}

// ---------------------------------------------------------------------------
// prep: one wave per output row. rows [0,2048): audio; [2048, 2048+16*2112): visual
// visual padded row layout per y: t*208 + v, v in [196,208) zero; rows [2080,2112) zero.
// visual rows written with 16B-unit XOR swizzle (unit ^ (row&7)) within the 512B row.
__global__ __launch_bounds__(512) void prep_kernel(const float* __restrict__ audio,
                                                   const float* __restrict__ visual,
                                                   char* __restrict__ ws)
{
    const int wrow = blockIdx.x * 8 + (threadIdx.x >> 6);
    const int lane = threadIdx.x & 63;
    if (wrow < 2048) {
        const float4 v = *(const float4*)(audio + (size_t)wrow * 256 + lane * 4);
        float ss = v.x*v.x + v.y*v.y + v.z*v.z + v.w*v.w;
        #pragma unroll
        for (int m = 1; m < 64; m <<= 1) ss += __shfl_xor(ss, m);
        const float sc = 1.0f / fmaxf(sqrtf(ss), 1e-12f);
        ushort4 o;
        o.x = f2bf(v.x*sc); o.y = f2bf(v.y*sc); o.z = f2bf(v.z*sc); o.w = f2bf(v.w*sc);
        *(ushort4*)(ws + WS_A_OFF + (size_t)wrow * 512 + lane * 8) = o;
    } else {
        const int vr  = wrow - 2048;          // global padded visual row
        const int y   = vr / 2112;
        const int rem = vr % 2112;
        const int t   = rem / 208;
        const int v   = rem % 208;
        ushort4 o = make_ushort4(0, 0, 0, 0);
        if (t < 10 && v < 196) {
            const float4 f = *(const float4*)(visual + (size_t)((y*10 + t)*196 + v) * 256 + lane * 4);
            float ss = f.x*f.x + f.y*f.y + f.z*f.z + f.w*f.w;
            #pragma unroll
            for (int m = 1; m < 64; m <<= 1) ss += __shfl_xor(ss, m);
            const float sc = 1.0f / fmaxf(sqrtf(ss), 1e-12f);
            o.x = f2bf(f.x*sc); o.y = f2bf(f.y*sc); o.z = f2bf(f.z*sc); o.w = f2bf(f.w*sc);
        }
        const int u   = lane >> 1;                 // 16B unit within row
        const int swz = u ^ (vr & 7);
        *(ushort4*)(ws + WS_V_OFF + (size_t)vr * 512 + (swz << 4) + ((lane & 1) << 3)) = o;
    }
}

// ---------------------------------------------------------------------------
// main: one block per (x,y) pair. 8 waves = 2 audio-halves x 4 visual-slots.
// Audio frags in registers (4 afrag x 8 ksteps). Visual chunks (64 rows=4 frags,
// 32KB) double-buffered via global_load_lds. Transposed MFMA: D[visual][audio].
__global__ __launch_bounds__(512, 2) void main_kernel(char* __restrict__ ws)
{
    extern __shared__ __align__(16) char smem[];
    const int tid  = threadIdx.x;
    const int lane = tid & 63;
    const int wid  = tid >> 6;
    const int aw   = wid & 1;    // audio half
    const int vw   = wid >> 1;   // visual frag slot within chunk
    const int l15  = lane & 15;
    const int kg   = lane >> 4;

    // XCD-aware pair mapping: 32 blocks per XCD share 2 y-panels
    const int b = blockIdx.x;
    const int xcd = b & 7, slot = b >> 3;
    const int y = xcd * 2 + (slot >> 4);
    const int x = slot & 15;

    // audio fragments -> registers (one-time, L2-resident)
    bf16x8 af[4][8];
    {
        const char* ab = ws + WS_A_OFF + (size_t)(x*128 + aw*64) * 512;
        #pragma unroll
        for (int a = 0; a < 4; ++a)
            #pragma unroll
            for (int k = 0; k < 8; ++k) {
                uint4 u = *(const uint4*)(ab + (a*16 + l15)*512 + k*64 + kg*16);
                af[a][k] = __builtin_bit_cast(bf16x8, u);
            }
    }

    int* part = (int*)(ws + WS_PART_OFF) + (x*16 + y) * 1280;   // [128 rows][10 t]
    const char* vsrc = ws + WS_V_OFF + (size_t)y * (2112 * 512);

    float nn = 0.f;
    float rmax[4] = {-3.4e38f, -3.4e38f, -3.4e38f, -3.4e38f};

    // prologue: stage chunk 0 into buf0
    {
        const char* s = vsrc + tid * 16;
        char* d = smem + tid * 16;
        gld_lds16(s, d); gld_lds16(s+8192, d+8192);
        gld_lds16(s+16384, d+16384); gld_lds16(s+24576, d+24576);
    }
    __syncthreads();   // compiler drains vmcnt before s_barrier

    int cur = 0;
    for (int c = 0; c < 33; ++c) {
        if (c + 1 < 33) {   // stage next chunk into the other buffer
            const char* s = vsrc + (size_t)(c+1) * 32768 + tid * 16;
            char* d = smem + ((cur ^ 1) << 15) + tid * 16;
            gld_lds16(s, d); gld_lds16(s+8192, d+8192);
            gld_lds16(s+16384, d+16384); gld_lds16(s+24576, d+24576);
        }
        const int frag = c * 4 + vw;            // global visual frag index [0,132)
        const int rowl = vw * 16 + l15;         // row within chunk buffer
        const char* bb = smem + (cur << 15) + rowl * 512;
        bf16x8 vf[8];
        #pragma unroll
        for (int k = 0; k < 8; ++k) {           // swizzled ds_read_b128, conflict-free
            const int u = k*4 + kg;
            uint4 q = *(const uint4*)(bb + ((u ^ (rowl & 7)) << 4));
            vf[k] = __builtin_bit_cast(bf16x8, q);
        }
        f32x4 acc[4] = {};
        #pragma unroll
        for (int k = 0; k < 8; ++k)
            #pragma unroll
            for (int a = 0; a < 4; ++a)
                acc[a] = __builtin_amdgcn_mfma_f32_16x16x32_bf16(vf[k], af[a][k], acc[a], 0, 0, 0);

        // fold: nonneg (pads give exact 0) + masked running max over visual
        const int t     = frag / 13;
        const int fm    = frag - t * 13;
        const int rbase = fm * 16 + kg * 4;
        const bool fv   = frag < 130;
        #pragma unroll
        for (int a = 0; a < 4; ++a)
            #pragma unroll
            for (int i = 0; i < 4; ++i) {
                const float s  = acc[a][i];
                const float ng = fminf(s, 0.f);
                nn += ng * ng;
                if (fv && (rbase + i) < 196) rmax[a] = fmaxf(rmax[a], s);
            }
        // flush running max at this wave's t boundary
        const int tn = (c < 32) ? (frag + 4) / 13 : -1;
        if (tn != t) {
            #pragma unroll
            for (int a = 0; a < 4; ++a) {
                float v = rmax[a];
                v = fmaxf(v, __shfl_xor(v, 16));
                v = fmaxf(v, __shfl_xor(v, 32));
                if (lane < 16 && t < 10)
                    atomicMax(part + (aw*64 + a*16 + l15) * 10 + t, fenc(v));
                rmax[a] = -3.4e38f;
            }
        }
        __syncthreads();   // drains staging vmcnt + orders buffer reuse
        cur ^= 1;
    }

    __threadfence();
    __syncthreads();

    // per-pair reduction: sum of per-(row,t) maxes + nonneg partial
    float sum = 0.f;
    for (int i = tid; i < 1280; i += 512) sum += fdec(part[i]);
    #pragma unroll
    for (int m = 32; m >= 1; m >>= 1) {
        sum += __shfl_xor(sum, m);
        nn  += __shfl_xor(nn, m);
    }
    float* red = (float*)smem;   // buffers are dead now
    if (lane == 0) { red[wid] = sum; red[8 + wid] = nn; }
    __syncthreads();
    if (tid == 0) {
        float S = 0.f, N = 0.f;
        for (int w = 0; w < 8; ++w) { S += red[w]; N += red[8 + w]; }
        ((float*)(ws + WS_CLIP_OFF))[x*16 + y] = S;
        ((float*)(ws + WS_NN_OFF))[x*16 + y]   = N;
    }
}

// ---------------------------------------------------------------------------
// final: 16x16 InfoNCE + regularizers -> 3 scalars
__global__ void final_kernel(const char* __restrict__ ws,
                             const float* __restrict__ temp,
                             float* __restrict__ out)
{
    __shared__ float cs[16][17];
    __shared__ float nnred[256];
    __shared__ float lse_r[16], lse_c[16];
    const int tid = threadIdx.x;
    const float T = temp[0];
    cs[tid >> 4][tid & 15] = ((const float*)(ws + WS_CLIP_OFF))[tid] / (1280.0f * T);
    nnred[tid] = ((const float*)(ws + WS_NN_OFF))[tid];
    __syncthreads();
    for (int s = 128; s > 0; s >>= 1) {
        if (tid < s) nnred[tid] += nnred[tid + s];
        __syncthreads();
    }
    if (tid < 16) {
        float m = -3.4e38f;
        for (int j = 0; j < 16; ++j) m = fmaxf(m, cs[tid][j]);
        float s = 0.f;
        for (int j = 0; j < 16; ++j) s += expf(cs[tid][j] - m);
        lse_r[tid] = m + logf(s);
    } else if (tid < 32) {
        const int c = tid - 16;
        float m = -3.4e38f;
        for (int j = 0; j < 16; ++j) m = fmaxf(m, cs[j][c]);
        float s = 0.f;
        for (int j = 0; j < 16; ++j) s += expf(cs[j][c] - m);
        lse_c[c] = m + logf(s);
    }
    __syncthreads();
    if (tid == 0) {
        float acc = 0.f;
        for (int i = 0; i < 16; ++i)
            acc += (lse_r[i] - cs[i][i]) + (lse_c[i] - cs[i][i]);
        const float contrastive = 0.5f * acc * (1.0f / 16.0f);
        const float l_nonneg = nnred[0] / (64225280.0f * T * T);
        const float lt = logf(T);
        float tl = fmaxf(-lt, 0.f); tl = tl * tl; tl = tl * tl;
        float th = fmaxf(lt - 1.0986122886681098f, 0.f); th = th * th; th = th * th;
        const float reg = l_nonneg + tl + th;
        out[0] = contrastive + 0.3f * reg;
        out[1] = contrastive;
        out[2] = reg;
    }
}

// ---------------------------------------------------------------------------
extern "C" void kernel_launch(void* const* d_in, const int* in_sizes, int n_in,
                              void* d_out, int out_size, void* d_ws, size_t ws_size,
                              hipStream_t stream)
{
    const float* audio  = (const float*)d_in[0];
    const float* visual = (const float*)d_in[1];
    const float* temp   = (const float*)d_in[2];
    char* ws = (char*)d_ws;

    // init per-(row,t) max slots to a very negative encoded value (0x80808080)
    hipMemsetAsync(ws + WS_PART_OFF, 0x80, (size_t)256 * 1280 * 4, stream);

    prep_kernel<<<4480, 512, 0, stream>>>(audio, visual, ws);       // 35840 rows / 8 waves
    main_kernel<<<256, 512, 65536, stream>>>(ws);                   // one block per pair
    final_kernel<<<1, 256, 0, stream>>>(ws, temp, (float*)d_out);
}